// Round 17
// baseline (441.367 us; speedup 1.0000x reference)
//
#include <hip/hip_runtime.h>
#include <stdint.h>

#define HW    480
#define KS    24
#define CH    3
#define HO    457            // 480-24+1
#define NPOS  (HO*HO)        // 208849
#define NP    400
#define PS    (CH*KS*KS)     // 1728
#define SIG   1e-6f
#define NSQ   54             // exact K32 steps: 1728/32
#define NMT   14             // 32-patch MFMA tiles (448 padded patches)
#define NIY   115            // ceil(457/4) row-quads
#define NGRP  (NIY*8*4)      // 3680: (iy,jx,row-in-quad) coarse groups (64 j each)
#define DELTA 4e-3f          // ~11 sigma of int8 coarse corr error (3.5e-4)
#define QS    28.0f          // int8 scale (clip at 127/28 = 4.54 sigma)
#define IS2   (1.0f/(QS*QS))
#define PB    2608           // LDS plane stride bytes (27*96=2592 -> pad, 16-aligned)

typedef __attribute__((ext_vector_type(4)))  int  int4v;
typedef __attribute__((ext_vector_type(16))) int  int16v;
typedef unsigned int uint;
typedef unsigned char uchar;
typedef unsigned long long ull;

static __device__ __forceinline__ char q8(float v) {
    float s = rintf(v * QS);
    s = fminf(127.f, fmaxf(-127.f, s));
    return (char)(int)s;
}
static __device__ __forceinline__ uint mono(float f) {      // order-preserving f32->u32
    uint u = __float_as_uint(f);
    return (u & 0x80000000u) ? ~u : (u | 0x80000000u);
}
static __device__ __forceinline__ float unmono(uint u) {
    uint b = (u & 0x80000000u) ? (u & 0x7fffffffu) : ~u;
    return __uint_as_float(b);
}

// ---------------- fat prep kernel 1: repack + y-quant + colsum + packAq + stats ----
// packAq and stats read x_dec directly (same index transform as repack), so all
// five jobs depend only on raw inputs -> one launch.
__global__ void fat1_k(const float* __restrict__ x, const float* __restrict__ yd,
                       float* __restrict__ Wp, char* __restrict__ yq,
                       float* __restrict__ cs, float* __restrict__ cs2,
                       char* __restrict__ Aq,
                       float* __restrict__ meanX, float* __restrict__ denXa) {
    __shared__ float shs[4], shs2[4];
    int b = blockIdx.x;
    if (b < 2700) {                       // repack: x_dec patches -> Wp[p][c][kh][kw]
        int t = b * 256 + threadIdx.x;    // 2700*256 == NP*PS exactly
        int p = t / PS, e = t - p * PS;
        int c = e / (KS * KS);
        int r = (e / KS) % KS;
        int w = e % KS;
        int pr = p / 20, pc = p - pr * 20;
        Wp[t] = x[c * HW * HW + (pr * KS + r) * HW + (pc * KS + w)];
    } else if (b < 5400) {                // y_dec -> int8 (scale QS)
        int t = (b - 2700) * 256 + threadIdx.x;
        yq[t] = q8(yd[t]);
    } else if (b < 6257) {                // colsum: vertical 24-row sums
        int t = (b - 5400) * 256 + threadIdx.x;
        if (t >= HO * HW) return;
        int i = t / HW, w = t - i * HW;
        float s = 0.f, s2 = 0.f;
        for (int c = 0; c < CH; c++) {
            const float* base = yd + c * HW * HW + i * HW + w;
            for (int dh = 0; dh < KS; dh++) {
                float v = base[dh * HW];
                s += v; s2 += v * v;
            }
        }
        cs[t] = s; cs2[t] = s2;
    } else if (b < 9281) {                // packAq: A int8 fragments, exact K (from x)
        int id = (b - 6257) * 256 + threadIdx.x;   // 3024*256 == NMT*54*1024 exactly
        int e    = id & 15;
        int lane = (id >> 4) & 63;
        int f    = id >> 10;
        int s    = f % NSQ;
        int mtg  = f / NSQ;
        int kk = s * 32 + (lane >> 5) * 16 + e;
        int p  = mtg * 32 + (lane & 31);
        float v = 0.f;
        if (p < NP) {
            int c  = kk / (KS * KS);
            int r  = (kk / KS) % KS;
            int w  = kk % KS;
            int pr = p / 20, pc = p - pr * 20;
            v = x[c * HW * HW + (pr * KS + r) * HW + (pc * KS + w)];
        }
        Aq[id] = q8(v);
    } else {                              // stats for patch b-9281 (from x)
        int p = b - 9281;
        int pr = p / 20, pc = p - pr * 20;
        float s = 0.f, s2 = 0.f;
        for (int e = threadIdx.x; e < PS; e += 256) {
            int c = e / (KS * KS);
            int r = (e / KS) % KS;
            int w = e % KS;
            float v = x[c * HW * HW + (pr * KS + r) * HW + (pc * KS + w)];
            s += v; s2 += v * v;
        }
        for (int o = 32; o > 0; o >>= 1) { s += __shfl_down(s, o); s2 += __shfl_down(s2, o); }
        int lane = threadIdx.x & 63, wv = threadIdx.x >> 6;
        if (lane == 0) { shs[wv] = s; shs2[wv] = s2; }
        __syncthreads();
        if (threadIdx.x == 0) {
            float S = shs[0] + shs[1] + shs[2] + shs[3];
            float S2 = shs2[0] + shs2[1] + shs2[2] + shs2[3];
            float m = S / (float)PS;
            meanX[p] = m;
            denXa[p] = fabsf(S2 / (float)PS - m * m);
        }
    }
}

// ---------------- fat prep kernel 2: window (needs colsum) ----------------
__global__ void fat2_k(const float* __restrict__ cs, const float* __restrict__ cs2,
                       float* __restrict__ sumY, float* __restrict__ denYa) {
    int t = blockIdx.x * 256 + threadIdx.x;
    if (t >= NPOS) return;
    int i = t / HO, j = t - i * HO;
    const float* r  = cs  + i * HW + j;
    const float* r2 = cs2 + i * HW + j;
    float s = 0.f, s2 = 0.f;
    for (int d = 0; d < KS; d++) { s += r[d]; s2 += r2[d]; }
    sumY[t] = s;
    float ips = 1.0f / (float)PS;
    denYa[t] = fabsf(s2 * ips - (s * ips) * (s * ips));
}

// ---------------- phase1: coarse int8 correlation, per-group max ----------------
// BYTE-IDENTICAL to R16's corr1_k (passed, 314 us). grid(8=jx, 115=iy, 7=mtp).
__launch_bounds__(256, 3)
__global__ void corr1_k(const char* __restrict__ yq, const char* __restrict__ Aq,
                        const float* __restrict__ meanX, const float* __restrict__ denXa,
                        const float* __restrict__ sumY, const float* __restrict__ denYa,
                        uint* __restrict__ table) {
    __shared__ __align__(16) uchar S[8 * PB];   // 20864 B

    const int tid  = threadIdx.x;
    const int lane = tid & 63;
    const int g    = tid >> 6;      // wave = row within quad
    const int n    = lane & 31;
    const int kha  = lane >> 5;
    const int jx   = blockIdx.x;
    const int iy   = blockIdx.y;
    const int mtp  = blockIdx.z;
    const int j0   = 64 * jx;
    const int i0   = 4 * iy;
    const int i    = i0 + g;

    // per-(u,kha) in-plane byte offsets (row stride 96 B); all == 0 mod 8
    const int olo0 = kha ? 16  : 0,   ohi0 = kha ? 96  : 8;
    const int olo1 = kha ? 192 : 104, ohi1 = kha ? 200 : 112;
    const int olo2 = kha ? 296 : 208, ohi2 = kha ? 304 : 288;

    // base pointers with g pre-folded; per-q adds 384 (one add per q)
    const uchar* Bt0g = S + ((2 * n) & 7) * PB + ((2 * n) & ~7) + g * 96;
    const uchar* Bt1g = Bt0g + PB;   // t=1: plane+1, same base

    const char* A0 = Aq + ((size_t)(mtp * 2 + 0) * NSQ << 10) + lane * 16;
    const char* A1 = Aq + ((size_t)(mtp * 2 + 1) * NSQ << 10) + lane * 16;

    int16v acc[2][2];   // [mt][t]
#pragma unroll
    for (int mt = 0; mt < 2; mt++)
#pragma unroll
        for (int t = 0; t < 2; t++) acc[mt][t] = (int16v)0;

    for (int c = 0; c < CH; c++) {
        __syncthreads();
        // stage 27 rows x 96 B into 8 byte-shift planes (plane pi[b] = row[b+pi])
        for (int it = tid; it < 27 * 6; it += 256) {
            int row = it / 6;
            int gb  = (it - row * 6) * 16;
            int yr  = i0 + row;
            int gj  = j0 + gb;
            uint d[6];
            if (yr < HW && gj + 24 <= HW) {
                const uchar* src = (const uchar*)yq + ((size_t)(c * HW + yr)) * HW + gj;
                uint4 a = *(const uint4*)src;           // 16B-aligned (gj%16==0)
                uint2 bb = *(const uint2*)(src + 16);
                d[0] = a.x; d[1] = a.y; d[2] = a.z; d[3] = a.w; d[4] = bb.x; d[5] = bb.y;
            } else {
                uchar tmp[24];
#pragma unroll
                for (int e = 0; e < 24; e++) {
                    int col = gj + e;
                    tmp[e] = (yr < HW && col < HW)
                           ? ((const uchar*)yq)[((size_t)(c * HW + yr)) * HW + col] : (uchar)0;
                }
                const uint* tp = (const uint*)tmp;
#pragma unroll
                for (int e = 0; e < 6; e++) d[e] = tp[e];
            }
            int base = row * 96 + gb;
#pragma unroll
            for (int pi = 0; pi < 8; pi++) {
                const int a = pi >> 2;      // word offset
                const int r = pi & 3;       // byte shift within word
                uint4 w;
                if (r == 0)
                    w = make_uint4(d[a], d[a + 1], d[a + 2], d[a + 3]);
                else
                    w = make_uint4((d[a]     >> (8 * r)) | (d[a + 1] << (32 - 8 * r)),
                                   (d[a + 1] >> (8 * r)) | (d[a + 2] << (32 - 8 * r)),
                                   (d[a + 2] >> (8 * r)) | (d[a + 3] << (32 - 8 * r)),
                                   (d[a + 3] >> (8 * r)) | (d[a + 4] << (32 - 8 * r)));
                *(uint4*)&S[pi * PB + base] = w;
            }
        }
        __syncthreads();

        const char* A0c = A0 + ((size_t)(c * 18) << 10);
        const char* A1c = A1 + ((size_t)(c * 18) << 10);
        for (int q = 0; q < 6; q++) {
            // per-q pointers; loads at immediate offsets 0/1024/2048
            const char* A0q = A0c + ((size_t)(3 * q) << 10);
            const char* A1q = A1c + ((size_t)(3 * q) << 10);
            int4v a0v[3], a1v[3];
#pragma unroll
            for (int u = 0; u < 3; u++) {
                a0v[u] = *(const int4v*)(A0q + (u << 10));
                a1v[u] = *(const int4v*)(A1q + (u << 10));
            }
            const uchar* Bq0 = Bt0g + 384 * q;
            const uchar* Bq1 = Bt1g + 384 * q;
#pragma unroll
            for (int u = 0; u < 3; u++) {
                const int olo = (u == 0) ? olo0 : (u == 1) ? olo1 : olo2;
                const int ohi = (u == 0) ? ohi0 : (u == 1) ? ohi1 : ohi2;
#pragma unroll
                for (int t = 0; t < 2; t++) {
                    const uchar* Bq = t ? Bq1 : Bq0;
                    uint2 lo = *(const uint2*)(Bq + olo);
                    uint2 hi = *(const uint2*)(Bq + ohi);
                    int4v bv;
                    bv.x = (int)lo.x; bv.y = (int)lo.y; bv.z = (int)hi.x; bv.w = (int)hi.y;
                    acc[0][t] = __builtin_amdgcn_mfma_i32_32x32x32_i8(a0v[u], bv, acc[0][t], 0, 0, 0);
                    acc[1][t] = __builtin_amdgcn_mfma_i32_32x32x32_i8(a1v[u], bv, acc[1][t], 0, 0, 0);
                }
            }
        }
    }

    // ---- epilogue: coarse corr, per-(patch, group) max (rcp + float fmax) ----
    const int grp = (iy * 8 + jx) * 4 + g;
    const float c2 = 2.0f / (float)PS;
    const bool iok = i < HO;
    float sYv[2], rDv[2];
#pragma unroll
    for (int t = 0; t < 2; t++) {
        int j = j0 + 2 * n + t;
        bool ok = iok && (j < HO);
        sYv[t] = ok ? sumY[i * HO + j] : 0.f;
        rDv[t] = ok ? denYa[i * HO + j] : 0.f;
    }
    const bool jv0 = iok && (j0 + 2 * n + 0 < HO);
    const bool jv1 = iok && (j0 + 2 * n + 1 < HO);
#pragma unroll
    for (int mt = 0; mt < 2; mt++) {
        const int pbase = (mtp * 2 + mt) * 32;
#pragma unroll
        for (int r = 0; r < 16; r++) {
            int p = pbase + (r & 3) + 8 * (r >> 2) + 4 * kha;
            bool pok = p < NP;
            float mX = pok ? meanX[p] : 0.f;
            float dX = pok ? denXa[p] : 0.f;
            float bu = -3.0e38f;
#pragma unroll
            for (int t = 0; t < 2; t++) {
                bool ok = t ? jv1 : jv0;
                if (ok) {
                    float xy = (float)acc[mt][t][r] * IS2;
                    float numer = fmaf(-mX, sYv[t], xy) * c2 + SIG;
                    float rp = __builtin_amdgcn_rcpf(dX + rDv[t] + SIG);
                    bu = fmaxf(bu, numer * rp);
                }
            }
#pragma unroll
            for (int o = 1; o < 32; o <<= 1)
                bu = fmaxf(bu, __shfl_xor(bu, o));
            if (n == 0 && pok) table[p * NGRP + grp] = mono(bu);
        }
    }
}

// ---------------- final: per-patch flag + exact rescore + gather, fused ----------------
// 400 blocks, one per patch. Threshold from table, chunked flag collection in
// LDS (chunk=cap=2048 -> no overflow), inline fp32 rescore (one wave/group),
// block-local best, inline gather. No global atomics, no extra launches.
__global__ void final_k(const uint* __restrict__ table,
                        const float* __restrict__ Wp, const float* __restrict__ y_dec,
                        const float* __restrict__ meanX, const float* __restrict__ denXa,
                        const float* __restrict__ sumY, const float* __restrict__ denYa,
                        const float* __restrict__ y, float* __restrict__ out) {
    __shared__ uint sm[4];
    __shared__ float sthr;
    __shared__ uint fl[2048];
    __shared__ uint scnt;
    __shared__ ull sb4[4];

    const int p = blockIdx.x;
    const int tid = threadIdx.x;
    const int ln = tid & 63, wv = tid >> 6;
    const uint* trow = table + (size_t)p * NGRP;

    // pass A: per-patch coarse max -> threshold
    uint m = 0;
    for (int g = tid; g < NGRP; g += 256) {
        uint v = trow[g];
        m = v > m ? v : m;
    }
    for (int o = 32; o > 0; o >>= 1) { uint ot = __shfl_down(m, o); m = ot > m ? ot : m; }
    if (ln == 0) sm[wv] = m;
    __syncthreads();
    if (tid == 0) {
        uint mm = max(max(sm[0], sm[1]), max(sm[2], sm[3]));
        sthr = unmono(mm) - DELTA;
    }
    __syncthreads();
    const float thr = sthr;

    // pass B: chunked flag + rescore; per-wave running best in register
    ull wbest = 0;
    const float* wr = Wp + (size_t)p * PS;
    const float mX = meanX[p], dX = denXa[p];
    for (int cs0 = 0; cs0 < NGRP; cs0 += 2048) {
        if (tid == 0) scnt = 0;
        __syncthreads();
        int cend = cs0 + 2048 < NGRP ? cs0 + 2048 : NGRP;
        for (int g = cs0 + tid; g < cend; g += 256) {
            if (unmono(trow[g]) >= thr) fl[atomicAdd(&scnt, 1u)] = (uint)g;
        }
        __syncthreads();
        uint nf = scnt;
        for (uint fi = wv; fi < nf; fi += 4) {
            uint grp = fl[fi];
            int gq = grp & 3, bj = grp >> 2;
            int jx = bj & 7, iy = bj >> 3;
            int i = 4 * iy + gq;
            int j = 64 * jx + ln;
            ull pk = 0;
            if (i < HO && j < HO) {
                float dot = 0.f;
                for (int c = 0; c < CH; c++)
                    for (int kh = 0; kh < KS; kh++) {
                        const float* yr = y_dec + ((c * HW) + i + kh) * HW + j;
                        const float* wk = wr + (c * KS + kh) * KS;
#pragma unroll
                        for (int kw = 0; kw < KS; kw++) dot += wk[kw] * yr[kw];
                    }
                float corr = (2.0f * (dot - mX * sumY[i * HO + j]) * (1.0f / (float)PS) + SIG)
                           / (dX + denYa[i * HO + j] + SIG);
                uint idx = (uint)(i * HO + j);
                pk = ((ull)mono(corr) << 32) | (uint)(~idx);   // first-max tie-break via ~idx
            }
            for (int o = 32; o > 0; o >>= 1) { ull ot = __shfl_down(pk, o); pk = ot > pk ? ot : pk; }
            if (ln == 0) wbest = pk > wbest ? pk : wbest;
        }
        __syncthreads();
    }
    if (ln == 0) sb4[wv] = wbest;
    __syncthreads();

    // gather
    ull b0 = sb4[0] > sb4[1] ? sb4[0] : sb4[1];
    ull b1 = sb4[2] > sb4[3] ? sb4[2] : sb4[3];
    ull bb = b0 > b1 ? b0 : b1;
    uint idx = ~((uint)(bb & 0xFFFFFFFFull));
    int r = idx / HO, cc = idx - r * HO;
    int pr = p / 20, pc = p - pr * 20;
    for (int e = tid; e < PS; e += 256) {
        int c = e / (KS * KS);
        int kh = (e / KS) % KS;
        int kw = e % KS;
        out[c * HW * HW + (pr * KS + kh) * HW + (pc * KS + kw)] =
            y[c * HW * HW + (r + kh) * HW + (cc + kw)];
    }
}

// ---------------- launch ----------------
extern "C" void kernel_launch(void* const* d_in, const int* in_sizes, int n_in,
                              void* d_out, int out_size, void* d_ws, size_t ws_size,
                              hipStream_t stream) {
    const float* x_dec = (const float*)d_in[0];
    const float* y_dec = (const float*)d_in[1];
    const float* y     = (const float*)d_in[2];
    float* out = (float*)d_out;

    char* ws = (char*)d_ws;
    size_t off = 0;
    auto carve = [&](size_t bytes) -> void* {
        void* p = ws + off;
        off += (bytes + 255) & ~(size_t)255;
        return p;
    };
    float*  Wp    = (float*)carve((size_t)NP * PS * 4);           // 2.77 MB
    char*   yq    = (char*)carve((size_t)CH * HW * HW);           // 0.69 MB
    char*   Aq    = (char*)carve((size_t)NMT * NSQ * 1024);       // 0.77 MB
    float*  cs    = (float*)carve((size_t)HO * HW * 4);
    float*  cs2   = (float*)carve((size_t)HO * HW * 4);
    float*  sumY  = (float*)carve((size_t)NPOS * 4);
    float*  denYa = (float*)carve((size_t)NPOS * 4);
    float*  meanX = (float*)carve((size_t)NP * 4);
    float*  denXa = (float*)carve((size_t)NP * 4);
    uint*   table = (uint*)carve((size_t)NP * NGRP * 4);          // 5.89 MB

    fat1_k<<<9681, 256, 0, stream>>>(x_dec, y_dec, Wp, yq, cs, cs2, Aq, meanX, denXa);
    fat2_k<<<816, 256, 0, stream>>>(cs, cs2, sumY, denYa);

    dim3 grid(8, NIY, 7);
    corr1_k<<<grid, 256, 0, stream>>>(yq, Aq, meanX, denXa, sumY, denYa, table);

    final_k<<<NP, 256, 0, stream>>>(table, Wp, y_dec, meanX, denXa, sumY, denYa, y, out);
}

// Round 18
// 402.263 us; speedup vs baseline: 1.0972x; 1.0972x over previous
//
#include <hip/hip_runtime.h>
#include <stdint.h>

#define HW    480
#define KS    24
#define CH    3
#define HO    457            // 480-24+1
#define NPOS  (HO*HO)        // 208849
#define NP    400
#define PS    (CH*KS*KS)     // 1728
#define SIG   1e-6f
#define NSQ   54             // exact K32 steps: 1728/32
#define NMT   14             // 32-patch MFMA tiles (448 padded patches)
#define NIY   115            // ceil(457/4) row-quads
#define NGRP  (NIY*8*4)      // 3680: (iy,jx,row-in-quad) coarse groups (64 j each)
#define MAXF  16384
#define RGRID 4096           // rescore grid (stride loop over flags)
#define DELTA 4e-3f          // ~11 sigma of int8 coarse corr error (3.5e-4)
#define QS    28.0f          // int8 scale (clip at 127/28 = 4.54 sigma)
#define IS2   (1.0f/(QS*QS))
#define PB    2608           // LDS plane stride bytes (27*96=2592 -> pad, 16-aligned)

typedef __attribute__((ext_vector_type(4)))  int  int4v;
typedef __attribute__((ext_vector_type(16))) int  int16v;
typedef unsigned int uint;
typedef unsigned char uchar;
typedef unsigned long long ull;

static __device__ __forceinline__ char q8(float v) {
    float s = rintf(v * QS);
    s = fminf(127.f, fmaxf(-127.f, s));
    return (char)(int)s;
}
static __device__ __forceinline__ uint mono(float f) {      // order-preserving f32->u32
    uint u = __float_as_uint(f);
    return (u & 0x80000000u) ? ~u : (u | 0x80000000u);
}
static __device__ __forceinline__ float unmono(uint u) {
    uint b = (u & 0x80000000u) ? (u & 0x7fffffffu) : ~u;
    return __uint_as_float(b);
}

// ---------------- fat prep kernel 1: repack + y-quant + colsum ----------------
__global__ void fat1_k(const float* __restrict__ x, const float* __restrict__ yd,
                       float* __restrict__ Wp, char* __restrict__ yq,
                       float* __restrict__ cs, float* __restrict__ cs2) {
    int b = blockIdx.x;
    if (b < 2700) {                       // repack: x_dec patches -> Wp[p][c][kh][kw]
        int t = b * 256 + threadIdx.x;    // 2700*256 == NP*PS exactly
        int p = t / PS, e = t - p * PS;
        int c = e / (KS * KS);
        int r = (e / KS) % KS;
        int w = e % KS;
        int pr = p / 20, pc = p - pr * 20;
        Wp[t] = x[c * HW * HW + (pr * KS + r) * HW + (pc * KS + w)];
    } else if (b < 5400) {                // y_dec -> int8 (scale QS)
        int t = (b - 2700) * 256 + threadIdx.x;
        yq[t] = q8(yd[t]);
    } else {                              // colsum: vertical 24-row sums
        int t = (b - 5400) * 256 + threadIdx.x;
        if (t >= HO * HW) return;
        int i = t / HW, w = t - i * HW;
        float s = 0.f, s2 = 0.f;
        for (int c = 0; c < CH; c++) {
            const float* base = yd + c * HW * HW + i * HW + w;
            for (int dh = 0; dh < KS; dh++) {
                float v = base[dh * HW];
                s += v; s2 += v * v;
            }
        }
        cs[t] = s; cs2[t] = s2;
    }
}

// ---------------- fat prep kernel 2: stats + packAq + window + init ----------------
// Aq layout: byte id = ((mtg*54 + s)*64 + lane)*16 + e;
// A[m][k]: m = lane&31, k = (lane>>5)*16 + e, kk = 32s + k (flat [c][kh][kw]).
__global__ void fat2_k(const float* __restrict__ Wp,
                       const float* __restrict__ cs, const float* __restrict__ cs2,
                       float* __restrict__ meanX, float* __restrict__ denXa,
                       char* __restrict__ Aq,
                       float* __restrict__ sumY, float* __restrict__ denYa,
                       uint* __restrict__ cnt, ull* __restrict__ best) {
    __shared__ float shs[4], shs2[4];
    int b = blockIdx.x;
    if (b < 400) {                        // stats for patch b (+ init best/cnt)
        int p = b;
        if (threadIdx.x == 1) best[p] = 0ull;
        if (b == 0 && threadIdx.x == 2) *cnt = 0u;
        float s = 0.f, s2 = 0.f;
        for (int e = threadIdx.x; e < PS; e += 256) {
            float v = Wp[p * PS + e];
            s += v; s2 += v * v;
        }
        for (int o = 32; o > 0; o >>= 1) { s += __shfl_down(s, o); s2 += __shfl_down(s2, o); }
        int lane = threadIdx.x & 63, wv = threadIdx.x >> 6;
        if (lane == 0) { shs[wv] = s; shs2[wv] = s2; }
        __syncthreads();
        if (threadIdx.x == 0) {
            float S = shs[0] + shs[1] + shs[2] + shs[3];
            float S2 = shs2[0] + shs2[1] + shs2[2] + shs2[3];
            float m = S / (float)PS;
            meanX[p] = m;
            denXa[p] = fabsf(S2 / (float)PS - m * m);
        }
    } else if (b < 3424) {                // packAq: A int8 fragments, exact K
        int id = (b - 400) * 256 + threadIdx.x;   // 3024*256 == NMT*54*1024 exactly
        int e    = id & 15;
        int lane = (id >> 4) & 63;
        int f    = id >> 10;
        int s    = f % NSQ;
        int mtg  = f / NSQ;
        int kk = s * 32 + (lane >> 5) * 16 + e;
        int p  = mtg * 32 + (lane & 31);
        float v = (p < NP) ? Wp[p * PS + kk] : 0.f;
        Aq[id] = q8(v);
    } else {                              // window: horizontal 24-col sums
        int t = (b - 3424) * 256 + threadIdx.x;
        if (t >= NPOS) return;
        int i = t / HO, j = t - i * HO;
        const float* r  = cs  + i * HW + j;
        const float* r2 = cs2 + i * HW + j;
        float s = 0.f, s2 = 0.f;
        for (int d = 0; d < KS; d++) { s += r[d]; s2 += r2[d]; }
        sumY[t] = s;
        float ips = 1.0f / (float)PS;
        denYa[t] = fabsf(s2 * ips - (s * ips) * (s * ips));
    }
}

// ---------------- phase1: coarse int8 correlation, per-group max ----------------
// grid(8=jx, 115=iy, 7=mtp). Wave g = row i0+g; 64 patches (mt2) x 64 pos
// (j = 64*jx + 2n + t) x 1 row. mfma_i32_32x32x32_i8, floor 83 us.
// B: 8 byte-shift LDS planes; lane n shift t reads plane ((2n+t)&7) at
// 8B-aligned base (2n)&~7 -> 2 aligned ds_read_b64 per frag, immediate offsets.
// Epilogue: rcp + float fmax reduce, mono once per (mt,r).
__launch_bounds__(256, 3)
__global__ void corr1_k(const char* __restrict__ yq, const char* __restrict__ Aq,
                        const float* __restrict__ meanX, const float* __restrict__ denXa,
                        const float* __restrict__ sumY, const float* __restrict__ denYa,
                        uint* __restrict__ table) {
    __shared__ __align__(16) uchar S[8 * PB];   // 20864 B

    const int tid  = threadIdx.x;
    const int lane = tid & 63;
    const int g    = tid >> 6;      // wave = row within quad
    const int n    = lane & 31;
    const int kha  = lane >> 5;
    const int jx   = blockIdx.x;
    const int iy   = blockIdx.y;
    const int mtp  = blockIdx.z;
    const int j0   = 64 * jx;
    const int i0   = 4 * iy;
    const int i    = i0 + g;

    // per-(u,kha) in-plane byte offsets (row stride 96 B); all == 0 mod 8
    const int olo0 = kha ? 16  : 0,   ohi0 = kha ? 96  : 8;
    const int olo1 = kha ? 192 : 104, ohi1 = kha ? 200 : 112;
    const int olo2 = kha ? 296 : 208, ohi2 = kha ? 304 : 288;

    // base pointers with g pre-folded; per-q adds 384 (one add per q)
    const uchar* Bt0g = S + ((2 * n) & 7) * PB + ((2 * n) & ~7) + g * 96;
    const uchar* Bt1g = Bt0g + PB;   // t=1: plane+1, same base

    const char* A0 = Aq + ((size_t)(mtp * 2 + 0) * NSQ << 10) + lane * 16;
    const char* A1 = Aq + ((size_t)(mtp * 2 + 1) * NSQ << 10) + lane * 16;

    int16v acc[2][2];   // [mt][t]
#pragma unroll
    for (int mt = 0; mt < 2; mt++)
#pragma unroll
        for (int t = 0; t < 2; t++) acc[mt][t] = (int16v)0;

    for (int c = 0; c < CH; c++) {
        __syncthreads();
        // stage 27 rows x 96 B into 8 byte-shift planes (plane pi[b] = row[b+pi])
        for (int it = tid; it < 27 * 6; it += 256) {
            int row = it / 6;
            int gb  = (it - row * 6) * 16;
            int yr  = i0 + row;
            int gj  = j0 + gb;
            uint d[6];
            if (yr < HW && gj + 24 <= HW) {
                const uchar* src = (const uchar*)yq + ((size_t)(c * HW + yr)) * HW + gj;
                uint4 a = *(const uint4*)src;           // 16B-aligned (gj%16==0)
                uint2 bb = *(const uint2*)(src + 16);
                d[0] = a.x; d[1] = a.y; d[2] = a.z; d[3] = a.w; d[4] = bb.x; d[5] = bb.y;
            } else {
                uchar tmp[24];
#pragma unroll
                for (int e = 0; e < 24; e++) {
                    int col = gj + e;
                    tmp[e] = (yr < HW && col < HW)
                           ? ((const uchar*)yq)[((size_t)(c * HW + yr)) * HW + col] : (uchar)0;
                }
                const uint* tp = (const uint*)tmp;
#pragma unroll
                for (int e = 0; e < 6; e++) d[e] = tp[e];
            }
            int base = row * 96 + gb;
#pragma unroll
            for (int pi = 0; pi < 8; pi++) {
                const int a = pi >> 2;      // word offset
                const int r = pi & 3;       // byte shift within word
                uint4 w;
                if (r == 0)
                    w = make_uint4(d[a], d[a + 1], d[a + 2], d[a + 3]);
                else
                    w = make_uint4((d[a]     >> (8 * r)) | (d[a + 1] << (32 - 8 * r)),
                                   (d[a + 1] >> (8 * r)) | (d[a + 2] << (32 - 8 * r)),
                                   (d[a + 2] >> (8 * r)) | (d[a + 3] << (32 - 8 * r)),
                                   (d[a + 3] >> (8 * r)) | (d[a + 4] << (32 - 8 * r)));
                *(uint4*)&S[pi * PB + base] = w;
            }
        }
        __syncthreads();

        const char* A0c = A0 + ((size_t)(c * 18) << 10);
        const char* A1c = A1 + ((size_t)(c * 18) << 10);
        for (int q = 0; q < 6; q++) {
            // per-q pointers; loads at immediate offsets 0/1024/2048
            const char* A0q = A0c + ((size_t)(3 * q) << 10);
            const char* A1q = A1c + ((size_t)(3 * q) << 10);
            int4v a0v[3], a1v[3];
#pragma unroll
            for (int u = 0; u < 3; u++) {
                a0v[u] = *(const int4v*)(A0q + (u << 10));
                a1v[u] = *(const int4v*)(A1q + (u << 10));
            }
            const uchar* Bq0 = Bt0g + 384 * q;
            const uchar* Bq1 = Bt1g + 384 * q;
#pragma unroll
            for (int u = 0; u < 3; u++) {
                const int olo = (u == 0) ? olo0 : (u == 1) ? olo1 : olo2;
                const int ohi = (u == 0) ? ohi0 : (u == 1) ? ohi1 : ohi2;
#pragma unroll
                for (int t = 0; t < 2; t++) {
                    const uchar* Bq = t ? Bq1 : Bq0;
                    uint2 lo = *(const uint2*)(Bq + olo);
                    uint2 hi = *(const uint2*)(Bq + ohi);
                    int4v bv;
                    bv.x = (int)lo.x; bv.y = (int)lo.y; bv.z = (int)hi.x; bv.w = (int)hi.y;
                    acc[0][t] = __builtin_amdgcn_mfma_i32_32x32x32_i8(a0v[u], bv, acc[0][t], 0, 0, 0);
                    acc[1][t] = __builtin_amdgcn_mfma_i32_32x32x32_i8(a1v[u], bv, acc[1][t], 0, 0, 0);
                }
            }
        }
    }

    // ---- epilogue: coarse corr, per-(patch, group) max (rcp + float fmax) ----
    const int grp = (iy * 8 + jx) * 4 + g;
    const float c2 = 2.0f / (float)PS;
    const bool iok = i < HO;
    float sYv[2], rDv[2];
#pragma unroll
    for (int t = 0; t < 2; t++) {
        int j = j0 + 2 * n + t;
        bool ok = iok && (j < HO);
        sYv[t] = ok ? sumY[i * HO + j] : 0.f;
        rDv[t] = ok ? denYa[i * HO + j] : 0.f;
    }
    const bool jv0 = iok && (j0 + 2 * n + 0 < HO);
    const bool jv1 = iok && (j0 + 2 * n + 1 < HO);
#pragma unroll
    for (int mt = 0; mt < 2; mt++) {
        const int pbase = (mtp * 2 + mt) * 32;
#pragma unroll
        for (int r = 0; r < 16; r++) {
            int p = pbase + (r & 3) + 8 * (r >> 2) + 4 * kha;
            bool pok = p < NP;
            float mX = pok ? meanX[p] : 0.f;
            float dX = pok ? denXa[p] : 0.f;
            float bu = -3.0e38f;
#pragma unroll
            for (int t = 0; t < 2; t++) {
                bool ok = t ? jv1 : jv0;
                if (ok) {
                    float xy = (float)acc[mt][t][r] * IS2;
                    float numer = fmaf(-mX, sYv[t], xy) * c2 + SIG;
                    float rp = __builtin_amdgcn_rcpf(dX + rDv[t] + SIG);
                    bu = fmaxf(bu, numer * rp);
                }
            }
#pragma unroll
            for (int o = 1; o < 32; o <<= 1)
                bu = fmaxf(bu, __shfl_xor(bu, o));
            if (n == 0 && pok) table[p * NGRP + grp] = mono(bu);
        }
    }
}

// ---------------- phase2a: per-patch threshold + flagged-group emission ----------------
__global__ void flag_k(const uint* __restrict__ table,
                       uint* __restrict__ flags, uint* __restrict__ cnt) {
    __shared__ uint sm[4];
    __shared__ float sthr;
    int p = blockIdx.x;
    uint m = 0;
    for (int g = threadIdx.x; g < NGRP; g += 256) {
        uint v = table[p * NGRP + g];
        m = v > m ? v : m;
    }
    for (int o = 32; o > 0; o >>= 1) { uint ot = __shfl_down(m, o); m = ot > m ? ot : m; }
    int lane = threadIdx.x & 63, wv = threadIdx.x >> 6;
    if (lane == 0) sm[wv] = m;
    __syncthreads();
    if (threadIdx.x == 0) {
        uint mm = max(max(sm[0], sm[1]), max(sm[2], sm[3]));
        sthr = unmono(mm) - DELTA;
    }
    __syncthreads();
    float thr = sthr;
    for (int g = threadIdx.x; g < NGRP; g += 256) {
        if (unmono(table[p * NGRP + g]) >= thr) {
            uint idx = atomicAdd(cnt, 1u);
            if (idx < MAXF) flags[idx] = (uint)(p * NGRP + g);
        }
    }
}

// ---------------- phase2b: exact fp32 rescoring of flagged groups ----------------
// Grid RGRID with stride loop (nflag typically << MAXF).
__launch_bounds__(64)
__global__ void rescore_k(const float* __restrict__ Wp, const float* __restrict__ y_dec,
                          const float* __restrict__ meanX, const float* __restrict__ denXa,
                          const float* __restrict__ sumY, const float* __restrict__ denYa,
                          const uint* __restrict__ flags, const uint* __restrict__ cnt,
                          ull* __restrict__ best) {
    uint nflag = *cnt; if (nflag > MAXF) nflag = MAXF;
    for (uint fb = blockIdx.x; fb < nflag; fb += RGRID) {
        uint f = flags[fb];
        int p = f / NGRP, grp = f - p * NGRP;
        int g = grp & 3, bj = grp >> 2;
        int jx = bj & 7, iy = bj >> 3;
        int i = 4 * iy + g;
        int j = 64 * jx + threadIdx.x;
        ull pk = 0;
        if (i < HO && j < HO) {
            float dot = 0.f;
            const float* wr = Wp + p * PS;
            for (int c = 0; c < CH; c++)
                for (int kh = 0; kh < KS; kh++) {
                    const float* yr = y_dec + ((c * HW) + i + kh) * HW + j;
                    const float* wk = wr + (c * KS + kh) * KS;
#pragma unroll
                    for (int kw = 0; kw < KS; kw++) dot += wk[kw] * yr[kw];
                }
            float corr = (2.0f * (dot - meanX[p] * sumY[i * HO + j]) * (1.0f / (float)PS) + SIG)
                       / (denXa[p] + denYa[i * HO + j] + SIG);
            uint idx = (uint)(i * HO + j);
            pk = ((ull)mono(corr) << 32) | (uint)(~idx);   // first-max tie-break via ~idx
        }
        for (int o = 32; o > 0; o >>= 1) { ull ot = __shfl_down(pk, o); pk = ot > pk ? ot : pk; }
        if (threadIdx.x == 0) atomicMax(&best[p], pk);
    }
}

// ---------------- gather ----------------
__global__ void gather_k(const float* __restrict__ y,
                         const ull* __restrict__ best,
                         float* __restrict__ out) {
    int p = blockIdx.x;
    uint idx = ~((uint)(best[p] & 0xFFFFFFFFull));
    int r = idx / HO, cc = idx - r * HO;
    int pr = p / 20, pc = p - pr * 20;
    for (int e = threadIdx.x; e < PS; e += 256) {
        int c = e / (KS * KS);
        int kh = (e / KS) % KS;
        int kw = e % KS;
        out[c * HW * HW + (pr * KS + kh) * HW + (pc * KS + kw)] =
            y[c * HW * HW + (r + kh) * HW + (cc + kw)];
    }
}

// ---------------- launch ----------------
extern "C" void kernel_launch(void* const* d_in, const int* in_sizes, int n_in,
                              void* d_out, int out_size, void* d_ws, size_t ws_size,
                              hipStream_t stream) {
    const float* x_dec = (const float*)d_in[0];
    const float* y_dec = (const float*)d_in[1];
    const float* y     = (const float*)d_in[2];
    float* out = (float*)d_out;

    char* ws = (char*)d_ws;
    size_t off = 0;
    auto carve = [&](size_t bytes) -> void* {
        void* p = ws + off;
        off += (bytes + 255) & ~(size_t)255;
        return p;
    };
    float*  Wp    = (float*)carve((size_t)NP * PS * 4);           // 2.77 MB
    char*   yq    = (char*)carve((size_t)CH * HW * HW);           // 0.69 MB
    char*   Aq    = (char*)carve((size_t)NMT * NSQ * 1024);       // 0.77 MB
    float*  cs    = (float*)carve((size_t)HO * HW * 4);
    float*  cs2   = (float*)carve((size_t)HO * HW * 4);
    float*  sumY  = (float*)carve((size_t)NPOS * 4);
    float*  denYa = (float*)carve((size_t)NPOS * 4);
    float*  meanX = (float*)carve((size_t)NP * 4);
    float*  denXa = (float*)carve((size_t)NP * 4);
    uint*   table = (uint*)carve((size_t)NP * NGRP * 4);          // 5.89 MB
    uint*   flags = (uint*)carve((size_t)MAXF * 4);
    uint*   cnt   = (uint*)carve(256);
    ull*    best  = (ull*)carve((size_t)NP * 8);

    fat1_k<<<6257, 256, 0, stream>>>(x_dec, y_dec, Wp, yq, cs, cs2);
    fat2_k<<<4240, 256, 0, stream>>>(Wp, cs, cs2, meanX, denXa, Aq, sumY, denYa, cnt, best);

    dim3 grid(8, NIY, 7);
    corr1_k<<<grid, 256, 0, stream>>>(yq, Aq, meanX, denXa, sumY, denYa, table);

    flag_k<<<NP, 256, 0, stream>>>(table, flags, cnt);
    rescore_k<<<RGRID, 64, 0, stream>>>(Wp, y_dec, meanX, denXa, sumY, denYa, flags, cnt, best);

    gather_k<<<NP, 256, 0, stream>>>(y, best, out);
}